// Round 11
// baseline (89.120 us; speedup 1.0000x reference)
//
#include <hip/hip_runtime.h>
#include <hip/hip_bf16.h>

// MeanPooling: out[b,e,d] = (sum_l map[b,e,l]*doc[b,l,d]) / lens[b,e]
// B=16, E=256, L=4096 (=K), D=512. fp32 in/out, bf16 MFMA inside.
//
// R11: per-CU delivery is capped at ~16 B/cy (R10 measurement; R8 showed the
// cap is per-CU, not chip-wide). Time = logical bytes / (256 CU x 16 B/cy).
// So: cut logical traffic 536 -> 268 MB with BM=256 (full E: doc read ONCE,
// emap twice). KSPLIT=8, grid 256 = 16b x 2dt x 8ks, 1 block/CU, 8 waves.
//  - Wave tile 128x64 (wr=w>>2, wc=w&3), acc[8][4] f32x4 = 128 VGPR.
//  - Single staging reg-set (fits regs; delivery 4096cy/k-step dwarfs the
//    ~400cy turnaround, ~91% utilization). R10's even/odd LDS dbuf phasing.
//  - Staging: B-waves(0-3) each own k-octet o=w: 8 x dwordx4 = full 1KB
//    k-rows (perfect contiguity); A-waves(4-7): 8 x dwordx4 = 8 x 128B row
//    segments. cvt-at-staging; LDS bf16 A'[256r][32k], B'[256d][32k]
//    (write-side transpose), R10-verified swizzle formulas.
//  - vmcnt(0) per half-iter (single set: drain IS the delivery wait),
//    raw s_barrier, lgkm0-before-barrier, clamped tail.
//  - Split-K x8 via memsetAsync + unsafeAtomicAdd (L2-local per XCD).

#define NB 16
#define NE 256
#define NL 4096
#define ND 512
#define KSPLIT 8
#define KPW (NL / KSPLIT)   // 512 per block
#define BK 32
#define NT (KPW / BK)       // 16 k-steps

using f32x4  = __attribute__((ext_vector_type(4))) float;
using u32x2  = __attribute__((ext_vector_type(2))) unsigned;
using u32x4  = __attribute__((ext_vector_type(4))) unsigned;
using bf16x8 = __attribute__((ext_vector_type(8))) short;

static __device__ __forceinline__ unsigned bfbits(float x) {
  return (unsigned)__builtin_bit_cast(unsigned short, (__bf16)x);  // RNE
}
static __device__ __forceinline__ unsigned lds_u32(const void* p) {
  return (unsigned)(size_t)(const __attribute__((address_space(3))) void*)p;
}

#define GLOADX4(DST, PTR) \
  asm volatile("global_load_dwordx4 %0, %1, off" : "=v"(DST) : "v"(PTR))
#define DSW64(ADDR, D, OFF) \
  asm volatile("ds_write_b64 %0, %1 offset:" OFF :: "v"(ADDR), "v"(D) : "memory")
#define DSW128(ADDR, D, OFF) \
  asm volatile("ds_write_b128 %0, %1 offset:" OFF :: "v"(ADDR), "v"(D) : "memory")
#define DSR128(DST, ADDR, OFF) \
  asm volatile("ds_read_b128 %0, %1 offset:" OFF : "=v"(DST) : "v"(ADDR))
#define WAIT_VM0()  asm volatile("s_waitcnt vmcnt(0)" ::: "memory")
#define WAIT_LGKM() asm volatile("s_waitcnt lgkmcnt(0)" ::: "memory")
#define SB0()       __builtin_amdgcn_sched_barrier(0)

// one k-step's staging: 8 x dwordx4 per thread (role decides addresses)
#define STAGE_ISSUE(RS, T)                                                     \
  do {                                                                         \
    const float* p_ = gthr + (size_t)(T) * tstep;                              \
    GLOADX4(RS[0], p_ + st0[0]); GLOADX4(RS[1], p_ + st0[1]);                  \
    GLOADX4(RS[2], p_ + st0[2]); GLOADX4(RS[3], p_ + st0[3]);                  \
    GLOADX4(RS[4], p_ + st0[4]); GLOADX4(RS[5], p_ + st0[5]);                  \
    GLOADX4(RS[6], p_ + st0[6]); GLOADX4(RS[7], p_ + st0[7]);                  \
  } while (0)

// convert to bf16 and write into LDS buffer (OFFS = "0" or "32768")
#define STAGE_WRITE(RS, OFFS)                                                  \
  do {                                                                         \
    if (isB) {                                                                 \
      _Pragma("unroll") for (int j_ = 0; j_ < 4; ++j_) {                       \
        u32x4 wv_;                                                             \
        _Pragma("unroll") for (int k_ = 0; k_ < 4; ++k_)                       \
            wv_[k_] = bfbits(RS[2 * k_][j_]) | (bfbits(RS[2 * k_ + 1][j_]) << 16); \
        DSW128(wAddr[j_], wv_, OFFS);                                          \
      }                                                                        \
    } else {                                                                   \
      _Pragma("unroll") for (int i_ = 0; i_ < 8; ++i_) {                       \
        u32x2 wv_;                                                             \
        wv_[0] = bfbits(RS[i_][0]) | (bfbits(RS[i_][1]) << 16);                \
        wv_[1] = bfbits(RS[i_][2]) | (bfbits(RS[i_][3]) << 16);                \
        DSW64(wAddr[i_], wv_, OFFS);                                           \
      }                                                                        \
    }                                                                          \
  } while (0)

// 8 A frags + 4 B frags (b128, base regs AB/BB per buffer) + 32 MFMA
#define COMPUTE(AB, BB)                                                        \
  do {                                                                         \
    bf16x8 af_[8], bf_[4];                                                     \
    DSR128(af_[0], AB, "0");    DSR128(af_[1], AB, "1024");                    \
    DSR128(af_[2], AB, "2048"); DSR128(af_[3], AB, "3072");                    \
    DSR128(af_[4], AB, "4096"); DSR128(af_[5], AB, "5120");                    \
    DSR128(af_[6], AB, "6144"); DSR128(af_[7], AB, "7168");                    \
    DSR128(bf_[0], BB, "0");    DSR128(bf_[1], BB, "1024");                    \
    DSR128(bf_[2], BB, "2048"); DSR128(bf_[3], BB, "3072");                    \
    WAIT_LGKM();                                                               \
    SB0();                                                                     \
    __builtin_amdgcn_s_setprio(1);                                             \
    _Pragma("unroll") for (int m_ = 0; m_ < 8; ++m_)                           \
        _Pragma("unroll") for (int n_ = 0; n_ < 4; ++n_)                       \
            acc[m_][n_] = __builtin_amdgcn_mfma_f32_16x16x32_bf16(             \
                af_[m_], bf_[n_], acc[m_][n_], 0, 0, 0);                       \
    __builtin_amdgcn_s_setprio(0);                                             \
    SB0();                                                                     \
  } while (0)

__global__ __launch_bounds__(512, 2) void mp_gemm(const float* __restrict__ doc,
                                                  const float* __restrict__ emap,
                                                  const float* __restrict__ lens,
                                                  float* __restrict__ out) {
  // 2 bufs x (A' [256r][32k] bf16 16KB + B' [256d][32k] bf16 16KB) = 64KB
  __shared__ char smem[2 * 32768];

  int bid = (int)blockIdx.x;
  // XCD swizzle: XCD x owns logical [32x,32x+31] = 2 whole batches.
  int logical = (bid & 7) * 32 + (bid >> 3);
  int b  = logical >> 4;      // 16 batches
  int dt = (logical >> 3) & 1;  // d-tile of 256
  int ks = logical & 7;       // k-split x8; siblings adjacent -> same XCD

  int tid  = (int)threadIdx.x;
  int w    = tid >> 6;
  int wr   = w >> 2;          // wave row 0..1 (128 rows each)
  int wc   = w & 3;           // wave col 0..3 (64 cols each)
  int lane = tid & 63;
  int l15  = lane & 15;
  int g    = lane >> 4;

  unsigned ldsb = lds_u32(smem);
  bool isB = (tid < 256);     // waves 0-3 stage B, waves 4-7 stage A

  // ---- staging addresses (per role) ----
  const float* gthr;
  size_t tstep;
  int st0[8];
  unsigned wAddr[8];

  if (isB) {
    // wave o=w owns k-octet o; thread q=tid&63 owns d=4q..4q+3.
    // instr i: full k-row (k=8o+i) x 1KB contiguous d-range.
    int q = tid & 63, o = w;
    gthr = doc + ((size_t)b * NL + ks * KPW + 8 * o) * ND + dt * 256 + 4 * q;
    tstep = (size_t)BK * ND;
#pragma unroll
    for (int i = 0; i < 8; ++i) st0[i] = i * ND;
    // B' write: row d=4q+j, octet o at granule o^((d>>2)&3)=o^(q&3)
#pragma unroll
    for (int j = 0; j < 4; ++j)
      wAddr[j] = ldsb + 16384 + (4 * q + j) * 64 + (((o ^ q) & 3) << 4);
  } else {
    // thread v: rows rowb+32i (rowb=v>>3), k-chunk c=v&7 (16B fp32 = 4k)
    int v = tid - 256;
    int rowb = v >> 3, c = v & 7;
    gthr = emap + (size_t)(b * NE + rowb) * NL + ks * KPW + 4 * c;
    tstep = (size_t)BK;
#pragma unroll
    for (int i = 0; i < 8; ++i) st0[i] = i * 32 * NL;
    // A' write: row r, octet c>>1 at granule (c>>1)^(r&3), 8B parity c&1
#pragma unroll
    for (int i = 0; i < 8; ++i) {
      int r = rowb + 32 * i;
      wAddr[i] = ldsb + r * 64 + ((((c >> 1) ^ r) & 3) << 4) + (c & 1) * 8;
    }
  }

  // ---- fragment read base addrs (m/n strides are imm offsets: +1024) ----
  // A frag m: row = 128wr+16m+l15, octet g at granule g^(row&3); row&3=l15&3
  unsigned aRd0 = ldsb + (128 * wr + l15) * 64 + (((g ^ l15) & 3) << 4);
  unsigned aRd1 = aRd0 + 32768;
  // B frag n: d = 64wc+16n+l15, octet g at granule g^((d>>2)&3); (d>>2)&3
  // = (l15>>2)&3 for all n (16n, 64wc are 0 mod 4 after >>2... verified)
  unsigned bRd0 = ldsb + 16384 + (64 * wc + l15) * 64 + (((g ^ (l15 >> 2)) & 3) << 4);
  unsigned bRd1 = bRd0 + 32768;

  f32x4 acc[8][4] = {};
  f32x4 RS[8];

  // prologue: tile0 -> buf0
  STAGE_ISSUE(RS, 0);
  SB0();
  WAIT_VM0();
  SB0();
  STAGE_WRITE(RS, "0");
  WAIT_LGKM();

#pragma unroll 1
  for (int t = 0; t < NT; t += 2) {
    int p2 = t + 2 < NT ? t + 2 : NT - 1;  // clamped (tail-safe)
    // even: compute buf0(t); issue t+1; drain; write buf1 <- t+1
    __builtin_amdgcn_s_barrier();
    SB0();
    STAGE_ISSUE(RS, t + 1);
    SB0();
    COMPUTE(aRd0, bRd0);
    WAIT_VM0();
    SB0();
    STAGE_WRITE(RS, "32768");
    WAIT_LGKM();
    SB0();
    // odd: compute buf1(t+1); issue t+2; drain; write buf0 <- t+2
    __builtin_amdgcn_s_barrier();
    SB0();
    STAGE_ISSUE(RS, p2);
    SB0();
    COMPUTE(aRd1, bRd1);
    WAIT_VM0();
    SB0();
    STAGE_WRITE(RS, "0");
    WAIT_LGKM();
    SB0();
  }

  // epilogue: divide by lens, atomic-accumulate the k-split partial.
  // C/D frag: row = 128wr + 16m + 4g + i, col = dt*256 + 64wc + 16n + l15.
  const float* lb = lens + b * NE + 128 * wr;
  float* ob = out + (size_t)(b * NE + 128 * wr) * ND + dt * 256 + 64 * wc;
#pragma unroll
  for (int m = 0; m < 8; ++m) {
#pragma unroll
    for (int i = 0; i < 4; ++i) {
      int row = 16 * m + 4 * g + i;
      float inv = 1.0f / lb[row];
#pragma unroll
      for (int n = 0; n < 4; ++n)
        unsafeAtomicAdd(&ob[(size_t)row * ND + 16 * n + l15], acc[m][n][i] * inv);
    }
  }
}

extern "C" void kernel_launch(void* const* d_in, const int* in_sizes, int n_in,
                              void* d_out, int out_size, void* d_ws, size_t ws_size,
                              hipStream_t stream) {
  const float* doc  = (const float*)d_in[0];  // (B, L, D)
  const float* emap = (const float*)d_in[1];  // (B, E, L)
  const float* lens = (const float*)d_in[2];  // (B, E)
  float* out = (float*)d_out;                 // (B, E, D)
  hipMemsetAsync(out, 0, (size_t)NB * NE * ND * sizeof(float), stream);
  hipLaunchKernelGGL(mp_gemm, dim3(256), dim3(512), 0, stream, doc, emap, lens, out);
}